// Round 2
// baseline (257.491 us; speedup 1.0000x reference)
//
#include <hip/hip_runtime.h>
#include <hip/hip_bf16.h>

#define GAT_ALPHA 0.2f
#define LOG2E 1.4426950408889634f

typedef float f32x4 __attribute__((ext_vector_type(4)));
typedef int   i32x4 __attribute__((ext_vector_type(4)));
typedef short bf16x8 __attribute__((ext_vector_type(8)));

static constexpr int Nn  = 2048;
static constexpr int FIN = 256;
static constexpr int FO  = 128;

static __device__ __forceinline__ unsigned short f2bf(float x) {
    __hip_bfloat16 h = __float2bfloat16(x);
    return __builtin_bit_cast(unsigned short, h);
}
static __device__ __forceinline__ float bf2f(unsigned short u) {
    unsigned int v = ((unsigned int)u) << 16;
    return __builtin_bit_cast(float, v);
}

// ---------------------------------------------------------------------------
// Kernel 0 (prep): wa = W@a (both halves). Inits md_key[8] = 0 (key of -inf).
// ---------------------------------------------------------------------------
__global__ __launch_bounds__(256) void gat_prep(
        const float* __restrict__ W, const float* __restrict__ a,
        float* __restrict__ wa, unsigned int* __restrict__ md_key)
{
    __shared__ float pr[32][8];
    __shared__ float pd[32][8];
    const int t = threadIdx.x;
    const int kl = t >> 3, seg = t & 7;
    const int k = blockIdx.x * 32 + kl;
    float ps = 0.f, pv = 0.f;
    const float* wr = W + (size_t)k * FO + seg * 16;
    #pragma unroll
    for (int f = 0; f < 16; f += 4) {
        f32x4 wv = *(const f32x4*)(wr + f);
        f32x4 as = *(const f32x4*)(a + seg * 16 + f);
        f32x4 ad = *(const f32x4*)(a + FO + seg * 16 + f);
        ps += wv[0]*as[0] + wv[1]*as[1] + wv[2]*as[2] + wv[3]*as[3];
        pv += wv[0]*ad[0] + wv[1]*ad[1] + wv[2]*ad[2] + wv[3]*ad[3];
    }
    pr[kl][seg] = ps; pd[kl][seg] = pv;
    __syncthreads();
    if (t < 32) {
        float s = 0.f, d = 0.f;
        #pragma unroll
        for (int j = 0; j < 8; ++j) { s += pr[t][j]; d += pd[t][j]; }
        wa[blockIdx.x * 32 + t]       = s;
        wa[256 + blockIdx.x * 32 + t] = d;
    }
    if (blockIdx.x == 0 && t < 8) md_key[t] = 0u;   // key(-inf)
}

// ---------------------------------------------------------------------------
// Kernel 1: Wp = bf16(h@W) in PACKED MFMA-B-fragment layout:
//   elem index ((b*64 + v)*8 + nt)*512 + lane*8 + e, where for feature f and
//   node n: v=n>>5, nt=f>>4, lane=((n>>3)&3)*16 + (f&15), e=n&7.
// A wave's B-fragment load in gat_attn is then 1024 B fully contiguous.
// s_src/s_dst fp32-exact via wa; per-batch max(s_dst) via uint atomicMax.
// ---------------------------------------------------------------------------
__global__ __launch_bounds__(256) void gat_wh(
        const float* __restrict__ h, const float* __restrict__ W,
        const float* __restrict__ wa, unsigned short* __restrict__ Wp,
        float* __restrict__ s_src, float* __restrict__ s_dst,
        unsigned int* __restrict__ md_key)
{
    __shared__ unsigned short WT[FO][264];  // [f][k] bf16, padded
    __shared__ float wal[512];
    __shared__ float sred[64][4][2];
    __shared__ float red64[64];
    const int t  = threadIdx.x;
    const int b  = blockIdx.x & 7;
    const int n0 = (blockIdx.x >> 3) << 6;

    if (t < 128) *(f32x4*)&wal[t * 4] = *(const f32x4*)&wa[t * 4];
    #pragma unroll
    for (int c = 0; c < 32; ++c) {
        int flat = c * 1024 + t * 4;
        int k = flat >> 7, f = flat & 127;
        f32x4 wv = *(const f32x4*)&W[flat];
        WT[f + 0][k] = f2bf(wv[0]);
        WT[f + 1][k] = f2bf(wv[1]);
        WT[f + 2][k] = f2bf(wv[2]);
        WT[f + 3][k] = f2bf(wv[3]);
    }
    __syncthreads();

    {
        const int row = t >> 2, seg = t & 3;
        const float* hp  = h + ((size_t)(b * Nn + n0 + row)) * FIN + seg * 64;
        const float* was = &wal[seg * 64];
        const float* wad = &wal[256 + seg * 64];
        float ps = 0.f, pv = 0.f;
        #pragma unroll
        for (int j = 0; j < 64; j += 4) {
            f32x4 hv = *(const f32x4*)(hp + j);
            f32x4 sv = *(const f32x4*)(was + j);
            f32x4 dv = *(const f32x4*)(wad + j);
            ps += hv[0]*sv[0] + hv[1]*sv[1] + hv[2]*sv[2] + hv[3]*sv[3];
            pv += hv[0]*dv[0] + hv[1]*dv[1] + hv[2]*dv[2] + hv[3]*dv[3];
        }
        sred[row][seg][0] = ps;
        sred[row][seg][1] = pv;
    }
    __syncthreads();
    if (t < 64) {
        float s = sred[t][0][0] + sred[t][1][0] + sred[t][2][0] + sred[t][3][0];
        float d = sred[t][0][1] + sred[t][1][1] + sred[t][2][1] + sred[t][3][1];
        s_src[b * Nn + n0 + t] = s;
        s_dst[b * Nn + n0 + t] = d;
        red64[t] = d;
    }
    __syncthreads();
    if (t < 16) red64[t] = fmaxf(fmaxf(red64[t], red64[t + 16]),
                                 fmaxf(red64[t + 32], red64[t + 48]));
    __syncthreads();
    if (t == 0) {
        float m = red64[0];
        #pragma unroll
        for (int j = 1; j < 16; ++j) m = fmaxf(m, red64[j]);
        unsigned int bits = __builtin_bit_cast(unsigned int, m);
        unsigned int key  = (bits & 0x80000000u) ? ~bits : (bits | 0x80000000u);
        atomicMax(md_key + b, key);
    }

    const int w = t >> 6, lane = t & 63, n16 = lane & 15, quad = lane >> 4;
    const float* ha = h + ((size_t)(b * Nn + n0 + w * 16 + n16)) * FIN + quad * 8;
    f32x4 acc[8] = {};
    #pragma unroll
    for (int ks = 0; ks < 8; ++ks) {
        f32x4 h0 = *(const f32x4*)(ha + ks * 32);
        f32x4 h1 = *(const f32x4*)(ha + ks * 32 + 4);
        bf16x8 af;
        af[0] = (short)f2bf(h0[0]); af[1] = (short)f2bf(h0[1]);
        af[2] = (short)f2bf(h0[2]); af[3] = (short)f2bf(h0[3]);
        af[4] = (short)f2bf(h1[0]); af[5] = (short)f2bf(h1[1]);
        af[6] = (short)f2bf(h1[2]); af[7] = (short)f2bf(h1[3]);
        #pragma unroll
        for (int nt = 0; nt < 8; ++nt) {
            bf16x8 bfr = *(const bf16x8*)&WT[nt * 16 + n16][ks * 32 + quad * 8];
            acc[nt] = __builtin_amdgcn_mfma_f32_16x16x32_bf16(af, bfr, acc[nt], 0, 0, 0);
        }
    }
    // packed write: element (f = nt*16+n16, n = n0 + w*16 + quad*4 + rr)
    {
        const int v      = (n0 >> 5) + (w >> 1);
        const int quad_p = ((w & 1) << 1) + (quad >> 1);
        const int eoff   = (quad & 1) << 2;
        #pragma unroll
        for (int nt = 0; nt < 8; ++nt) {
            ushort4 pk;
            pk.x = f2bf(acc[nt][0]); pk.y = f2bf(acc[nt][1]);
            pk.z = f2bf(acc[nt][2]); pk.w = f2bf(acc[nt][3]);
            size_t idx = ((((size_t)(b << 6) + v) * 8 + nt) * 64 + quad_p * 16 + n16) * 8 + eoff;
            *(ushort4*)&Wp[idx] = pk;
        }
    }
}

// ---------------------------------------------------------------------------
// Kernel 2 (v5): barrier-free, LDS-free main loop; 16-row i-tiles.
// Grid 1024 = 128 i-tiles x 8 batches -> 4 blocks/CU (50% occupancy cap).
// Wave w owns j-window w*32 of each 128-j tile. Per lane (n16,quad):
//   - A fragment (P) computed in registers: row i0+n16, j = j0+w*32+quad*8..+8
//   - B fragment: ONE fully-coalesced 1024 B/wave load from packed Wp
// Denominator via shfl_xor + one LDS atomic per wave; small LDS epilogue.
// ---------------------------------------------------------------------------
__global__ __launch_bounds__(256, 4) void gat_attn(
        const int* __restrict__ adj, const unsigned short* __restrict__ Wp,
        const float* __restrict__ s_src, const float* __restrict__ s_dst,
        const unsigned int* __restrict__ md_key, float* __restrict__ out)
{
    constexpr int AS = 132;                        // accbuf row stride (f32)
    __shared__ __align__(16) float accbuf[2 * 16 * AS];   // 16896 B
    __shared__ float l_red[16];

    const int t = threadIdx.x, w = t >> 6, lane = t & 63;
    const int n16 = lane & 15, quad = lane >> 4;
    const int b  = blockIdx.x & 7;
    const int i0 = (blockIdx.x >> 3) << 4;

    if (t < 16) l_red[t] = 0.f;
    __syncthreads();

    const unsigned int key = md_key[b];
    const unsigned int mb  = (key & 0x80000000u) ? (key ^ 0x80000000u) : ~key;
    const float mdb = __builtin_bit_cast(float, mb);

    const float ssr = s_src[b * Nn + i0 + n16];
    const float tm  = ssr + mdb;
    const float mi  = fmaxf(tm, GAT_ALPHA * tm) * LOG2E;  // row upper bound
    const float sL  = ssr * LOG2E;

    const int jw = (w << 5) + (quad << 3);         // lane's j offset in tile
    const int* ap    = adj + ((size_t)(b * Nn + i0 + n16)) * Nn + jw;
    const float* dptr = s_dst + b * Nn + jw;
    // packed Wp: elem ((b*64 + s*4 + w)*8 + nt)*512 + lane*8
    const unsigned short* wp = Wp + ((size_t)b << 18) + ((size_t)w << 12) + (lane << 3);

    f32x4 acc[8] = {};
    float ls = 0.f;

    // adj prefetch: tile 0 (this lane's 8 j's for its row)
    i32x4 pa0 = *(const i32x4*)(ap);
    i32x4 pa1 = *(const i32x4*)(ap + 4);

    for (int s = 0; s < 16; ++s) {
        const int j0 = s << 7;
        // B fragments: 8 x 1024B-contiguous wave loads (L2-hot, batch==XCD)
        const unsigned short* wts = wp + (s << 14);
        bf16x8 bfr[8];
        #pragma unroll
        for (int nt = 0; nt < 8; ++nt)
            bfr[nt] = *(const bf16x8*)(wts + (nt << 9));
        // d-values (broadcast, L2-hot)
        f32x4 d0 = *(const f32x4*)(dptr + j0);
        f32x4 d1 = *(const f32x4*)(dptr + j0 + 4);
        // adj prefetch for next tile (stays in flight through exp+MFMA)
        const int jn = (s < 15) ? (j0 + 128) : 0;
        i32x4 na0 = *(const i32x4*)(ap + jn);
        i32x4 na1 = *(const i32x4*)(ap + jn + 4);

        // e-compute directly into A-fragment layout (8 consecutive j)
        bf16x8 af;
        #pragma unroll
        for (int j = 0; j < 4; ++j) {
            float u  = __builtin_fmaf(d0[j], LOG2E, sL);
            float lr = fmaxf(u, GAT_ALPHA * u);
            float e  = __builtin_amdgcn_exp2f(lr - mi);
            e = (pa0[j] > 0) ? e : 0.f;
            unsigned short us = f2bf(e);
            ls += bf2f(us); af[j] = (short)us;
        }
        #pragma unroll
        for (int j = 0; j < 4; ++j) {
            float u  = __builtin_fmaf(d1[j], LOG2E, sL);
            float lr = fmaxf(u, GAT_ALPHA * u);
            float e  = __builtin_amdgcn_exp2f(lr - mi);
            e = (pa1[j] > 0) ? e : 0.f;
            unsigned short us = f2bf(e);
            ls += bf2f(us); af[4 + j] = (short)us;
        }
        #pragma unroll
        for (int nt = 0; nt < 8; ++nt)
            acc[nt] = __builtin_amdgcn_mfma_f32_16x16x32_bf16(af, bfr[nt], acc[nt], 0, 0, 0);
        pa0 = na0; pa1 = na1;
    }

    // denominator: reduce per-lane partials across quads, one atomic per wave
    ls += __shfl_xor(ls, 16); ls += __shfl_xor(ls, 32);
    if (quad == 0) atomicAdd(&l_red[n16], ls);

    // cross-wave accumulator reduction: waves 0,1 write slots 0,1; 2,3 add
    float* slot = accbuf + (size_t)(w & 1) * 16 * AS;
    if (w < 2) {
        #pragma unroll
        for (int nt = 0; nt < 8; ++nt)
            #pragma unroll
            for (int rr = 0; rr < 4; ++rr)
                slot[(quad * 4 + rr) * AS + nt * 16 + n16] = acc[nt][rr];
    }
    __syncthreads();
    if (w >= 2) {
        #pragma unroll
        for (int nt = 0; nt < 8; ++nt)
            #pragma unroll
            for (int rr = 0; rr < 4; ++rr)
                slot[(quad * 4 + rr) * AS + nt * 16 + n16] += acc[nt][rr];
    }
    __syncthreads();
    // normalize + ELU + coalesced store
    float* ob = out + ((size_t)(b * Nn + i0)) * FO;
    #pragma unroll
    for (int c = 0; c < 2; ++c) {
        int flat = c * 1024 + t * 4;
        int m = flat >> 7, f = flat & 127;
        f32x4 v0 = *(const f32x4*)&accbuf[(size_t)m * AS + f];
        f32x4 v1 = *(const f32x4*)&accbuf[(size_t)16 * AS + m * AS + f];
        float l = l_red[m];
        f32x4 o;
        #pragma unroll
        for (int j = 0; j < 4; ++j) {
            float x = (v0[j] + v1[j]) / l;
            o[j] = x > 0.f ? x : expm1f(x);
        }
        *(f32x4*)&ob[(size_t)m * FO + f] = o;
    }
}

extern "C" void kernel_launch(void* const* d_in, const int* in_sizes, int n_in,
                              void* d_out, int out_size, void* d_ws, size_t ws_size,
                              hipStream_t stream)
{
    const float* h   = (const float*)d_in[0];
    const int*   adj = (const int*)d_in[1];
    const float* W   = (const float*)d_in[2];
    const float* a   = (const float*)d_in[3];
    float* out = (float*)d_out;

    char* ws = (char*)d_ws;
    unsigned short* Wp  = (unsigned short*)ws;                    // 4 MiB packed
    float* s_src        = (float*)(ws + 4194304);                 // 8 KiB
    float* s_dst        = (float*)(ws + 4259840);                 // 8 KiB
    float* wa           = (float*)(ws + 4325376);                 // 2 KiB
    unsigned int* md_key= (unsigned int*)(ws + 4327424);          // 32 B

    hipLaunchKernelGGL(gat_prep, dim3(8),    dim3(256), 0, stream, W, a, wa, md_key);
    hipLaunchKernelGGL(gat_wh,   dim3(256),  dim3(256), 0, stream, h, W, wa, Wp, s_src, s_dst, md_key);
    hipLaunchKernelGGL(gat_attn, dim3(1024), dim3(256), 0, stream, adj, Wp, s_src, s_dst, md_key, out);
}

// Round 3
// 256.326 us; speedup vs baseline: 1.0045x; 1.0045x over previous
//
#include <hip/hip_runtime.h>
#include <hip/hip_bf16.h>

#define GAT_ALPHA 0.2f
#define LOG2E 1.4426950408889634f

typedef float f32x4 __attribute__((ext_vector_type(4)));
typedef int   i32x4 __attribute__((ext_vector_type(4)));
typedef short bf16x8 __attribute__((ext_vector_type(8)));

static constexpr int Nn  = 2048;
static constexpr int FIN = 256;
static constexpr int FO  = 128;

static __device__ __forceinline__ unsigned short f2bf(float x) {
    __hip_bfloat16 h = __float2bfloat16(x);
    return __builtin_bit_cast(unsigned short, h);
}
static __device__ __forceinline__ float bf2f(unsigned short u) {
    unsigned int v = ((unsigned int)u) << 16;
    return __builtin_bit_cast(float, v);
}

// ---------------------------------------------------------------------------
// Kernel 0 (prep): wa = W@a (both halves). Inits md_key[8] = 0 (key of -inf).
// ---------------------------------------------------------------------------
__global__ __launch_bounds__(256) void gat_prep(
        const float* __restrict__ W, const float* __restrict__ a,
        float* __restrict__ wa, unsigned int* __restrict__ md_key)
{
    __shared__ float pr[32][8];
    __shared__ float pd[32][8];
    const int t = threadIdx.x;
    const int kl = t >> 3, seg = t & 7;
    const int k = blockIdx.x * 32 + kl;
    float ps = 0.f, pv = 0.f;
    const float* wr = W + (size_t)k * FO + seg * 16;
    #pragma unroll
    for (int f = 0; f < 16; f += 4) {
        f32x4 wv = *(const f32x4*)(wr + f);
        f32x4 as = *(const f32x4*)(a + seg * 16 + f);
        f32x4 ad = *(const f32x4*)(a + FO + seg * 16 + f);
        ps += wv[0]*as[0] + wv[1]*as[1] + wv[2]*as[2] + wv[3]*as[3];
        pv += wv[0]*ad[0] + wv[1]*ad[1] + wv[2]*ad[2] + wv[3]*ad[3];
    }
    pr[kl][seg] = ps; pd[kl][seg] = pv;
    __syncthreads();
    if (t < 32) {
        float s = 0.f, d = 0.f;
        #pragma unroll
        for (int j = 0; j < 8; ++j) { s += pr[t][j]; d += pd[t][j]; }
        wa[blockIdx.x * 32 + t]       = s;
        wa[256 + blockIdx.x * 32 + t] = d;
    }
    if (blockIdx.x == 0 && t < 8) md_key[t] = 0u;   // key(-inf)
}

// ---------------------------------------------------------------------------
// Kernel 1: Wp = bf16(h@W) in PACKED MFMA-B-fragment layout:
//   elem index ((b*64 + v)*8 + nt)*512 + lane*8 + e, where for feature f and
//   node n: v=n>>5, nt=f>>4, lane=((n>>3)&3)*16 + (f&15), e=n&7.
// s_src/s_dst fp32-exact via wa; per-batch max(s_dst) via uint atomicMax.
// ---------------------------------------------------------------------------
__global__ __launch_bounds__(256) void gat_wh(
        const float* __restrict__ h, const float* __restrict__ W,
        const float* __restrict__ wa, unsigned short* __restrict__ Wp,
        float* __restrict__ s_src, float* __restrict__ s_dst,
        unsigned int* __restrict__ md_key)
{
    __shared__ unsigned short WT[FO][264];  // [f][k] bf16, padded
    __shared__ float wal[512];
    __shared__ float sred[64][4][2];
    __shared__ float red64[64];
    const int t  = threadIdx.x;
    const int b  = blockIdx.x & 7;
    const int n0 = (blockIdx.x >> 3) << 6;

    if (t < 128) *(f32x4*)&wal[t * 4] = *(const f32x4*)&wa[t * 4];
    #pragma unroll
    for (int c = 0; c < 32; ++c) {
        int flat = c * 1024 + t * 4;
        int k = flat >> 7, f = flat & 127;
        f32x4 wv = *(const f32x4*)&W[flat];
        WT[f + 0][k] = f2bf(wv[0]);
        WT[f + 1][k] = f2bf(wv[1]);
        WT[f + 2][k] = f2bf(wv[2]);
        WT[f + 3][k] = f2bf(wv[3]);
    }
    __syncthreads();

    {
        const int row = t >> 2, seg = t & 3;
        const float* hp  = h + ((size_t)(b * Nn + n0 + row)) * FIN + seg * 64;
        const float* was = &wal[seg * 64];
        const float* wad = &wal[256 + seg * 64];
        float ps = 0.f, pv = 0.f;
        #pragma unroll
        for (int j = 0; j < 64; j += 4) {
            f32x4 hv = *(const f32x4*)(hp + j);
            f32x4 sv = *(const f32x4*)(was + j);
            f32x4 dv = *(const f32x4*)(wad + j);
            ps += hv[0]*sv[0] + hv[1]*sv[1] + hv[2]*sv[2] + hv[3]*sv[3];
            pv += hv[0]*dv[0] + hv[1]*dv[1] + hv[2]*dv[2] + hv[3]*dv[3];
        }
        sred[row][seg][0] = ps;
        sred[row][seg][1] = pv;
    }
    __syncthreads();
    if (t < 64) {
        float s = sred[t][0][0] + sred[t][1][0] + sred[t][2][0] + sred[t][3][0];
        float d = sred[t][0][1] + sred[t][1][1] + sred[t][2][1] + sred[t][3][1];
        s_src[b * Nn + n0 + t] = s;
        s_dst[b * Nn + n0 + t] = d;
        red64[t] = d;
    }
    __syncthreads();
    if (t < 16) red64[t] = fmaxf(fmaxf(red64[t], red64[t + 16]),
                                 fmaxf(red64[t + 32], red64[t + 48]));
    __syncthreads();
    if (t == 0) {
        float m = red64[0];
        #pragma unroll
        for (int j = 1; j < 16; ++j) m = fmaxf(m, red64[j]);
        unsigned int bits = __builtin_bit_cast(unsigned int, m);
        unsigned int key  = (bits & 0x80000000u) ? ~bits : (bits | 0x80000000u);
        atomicMax(md_key + b, key);
    }

    const int w = t >> 6, lane = t & 63, n16 = lane & 15, quad = lane >> 4;
    const float* ha = h + ((size_t)(b * Nn + n0 + w * 16 + n16)) * FIN + quad * 8;
    f32x4 acc[8] = {};
    #pragma unroll
    for (int ks = 0; ks < 8; ++ks) {
        f32x4 h0 = *(const f32x4*)(ha + ks * 32);
        f32x4 h1 = *(const f32x4*)(ha + ks * 32 + 4);
        bf16x8 af;
        af[0] = (short)f2bf(h0[0]); af[1] = (short)f2bf(h0[1]);
        af[2] = (short)f2bf(h0[2]); af[3] = (short)f2bf(h0[3]);
        af[4] = (short)f2bf(h1[0]); af[5] = (short)f2bf(h1[1]);
        af[6] = (short)f2bf(h1[2]); af[7] = (short)f2bf(h1[3]);
        #pragma unroll
        for (int nt = 0; nt < 8; ++nt) {
            bf16x8 bfr = *(const bf16x8*)&WT[nt * 16 + n16][ks * 32 + quad * 8];
            acc[nt] = __builtin_amdgcn_mfma_f32_16x16x32_bf16(af, bfr, acc[nt], 0, 0, 0);
        }
    }
    // packed write: element (f = nt*16+n16, n = n0 + w*16 + quad*4 + rr)
    {
        const int v      = (n0 >> 5) + (w >> 1);
        const int quad_p = ((w & 1) << 1) + (quad >> 1);
        const int eoff   = (quad & 1) << 2;
        #pragma unroll
        for (int nt = 0; nt < 8; ++nt) {
            ushort4 pk;
            pk.x = f2bf(acc[nt][0]); pk.y = f2bf(acc[nt][1]);
            pk.z = f2bf(acc[nt][2]); pk.w = f2bf(acc[nt][3]);
            size_t idx = ((((size_t)(b << 6) + v) * 8 + nt) * 64 + quad_p * 16 + n16) * 8 + eoff;
            *(ushort4*)&Wp[idx] = pk;
        }
    }
}

// ---------------------------------------------------------------------------
// Kernel 2 (v6): minimize per-CU VMEM line traffic (the measured wall).
// Grid 256 = 32 i-tiles(64 rows) x 8 batches -> 1 block/CU, batch==XCD.
// 512 threads = 8 waves = 4 row-groups x 2 j-windows; j-tile = 64.
// Per tile: block stages the 16 KB packed-Wp chunk into LDS ONCE
// (reg-staged, double-buffered, loads issued early / ds_write late),
// all 4 row-group waves share each B-fragment via conflict-free
// ds_read_b128. A-fragments (P) computed in registers from adj+s_dst.
// Per-CU traffic: Wp 512 KB + adj 512 KB (vs 2.5 MB in v5).
// ---------------------------------------------------------------------------
__global__ __launch_bounds__(512, 2) void gat_attn(
        const int* __restrict__ adj, const unsigned short* __restrict__ Wp,
        const float* __restrict__ s_src, const float* __restrict__ s_dst,
        const unsigned int* __restrict__ md_key, float* __restrict__ out)
{
    constexpr int AS = 132;                      // accbuf row stride (f32)
    __shared__ __align__(16) float smem_f[64 * AS];   // 33792 B; first 32 KB = stage bufs
    __shared__ float l_red[64];
    unsigned short* ldsw = (unsigned short*)smem_f;   // 2 x 8192 shorts

    const int t = threadIdx.x, w = t >> 6, lane = t & 63;
    const int n16 = lane & 15, quad = lane >> 4;
    const int rg = w & 3, jwin = w >> 2;
    const int b  = blockIdx.x & 7;
    const int i0 = (blockIdx.x >> 3) << 6;

    if (t < 64) l_red[t] = 0.f;

    const unsigned int key = md_key[b];
    const unsigned int mb  = (key & 0x80000000u) ? (key ^ 0x80000000u) : ~key;
    const float mdb = __builtin_bit_cast(float, mb);

    const int row = i0 + rg * 16 + n16;          // this lane's i-row
    const float ssr = s_src[b * Nn + row];
    const float tm  = ssr + mdb;
    const float mi  = fmaxf(tm, GAT_ALPHA * tm) * LOG2E;   // row upper bound
    const float sL  = ssr * LOG2E;

    const int jw = (jwin << 5) + (quad << 3);    // lane's j offset within tile
    const int* ap    = adj + ((size_t)(b * Nn + row)) * Nn + jw;
    const float* dptr = s_dst + b * Nn + jw;
    // packed Wp: batch base b*262144 shorts; tile s chunk = 8192 shorts;
    // thread t stages shorts [t*16, t*16+16)
    const unsigned short* wsrc = Wp + ((size_t)b << 18) + (t << 4);

    f32x4 acc[8] = {};
    float ls = 0.f;

    // prologue: stage tile 0 into buf 0; prefetch adj tile 0
    {
        f32x4 g0 = *(const f32x4*)(wsrc);
        f32x4 g1 = *(const f32x4*)(wsrc + 8);
        *(f32x4*)&ldsw[(t << 4)]     = g0;
        *(f32x4*)&ldsw[(t << 4) + 8] = g1;
    }
    i32x4 pa0 = *(const i32x4*)(ap);
    i32x4 pa1 = *(const i32x4*)(ap + 4);
    __syncthreads();

    for (int s = 0; s < 32; ++s) {
        const int j0  = s << 6;
        const int cur = s & 1, nxt = cur ^ 1;
        // d-values first (oldest outstanding -> shortest wait before exp)
        f32x4 d0 = *(const f32x4*)(dptr + j0);
        f32x4 d1 = *(const f32x4*)(dptr + j0 + 4);
        // issue stage loads for tile s+1 (consumed at loop bottom)
        f32x4 g0, g1;
        if (s < 31) {
            const unsigned short* src = wsrc + (s + 1) * 8192;
            g0 = *(const f32x4*)(src);
            g1 = *(const f32x4*)(src + 8);
        }
        // adj prefetch for tile s+1
        const int jn = (s < 31) ? ((s + 1) << 6) : 0;
        i32x4 na0 = *(const i32x4*)(ap + jn);
        i32x4 na1 = *(const i32x4*)(ap + jn + 4);

        // exp -> A fragment (8 consecutive j per lane)
        bf16x8 af;
        #pragma unroll
        for (int j = 0; j < 4; ++j) {
            float u  = __builtin_fmaf(d0[j], LOG2E, sL);
            float lr = fmaxf(u, GAT_ALPHA * u);
            float e  = __builtin_amdgcn_exp2f(lr - mi);
            e = (pa0[j] > 0) ? e : 0.f;
            unsigned short us = f2bf(e);
            ls += bf2f(us); af[j] = (short)us;
        }
        #pragma unroll
        for (int j = 0; j < 4; ++j) {
            float u  = __builtin_fmaf(d1[j], LOG2E, sL);
            float lr = fmaxf(u, GAT_ALPHA * u);
            float e  = __builtin_amdgcn_exp2f(lr - mi);
            e = (pa1[j] > 0) ? e : 0.f;
            unsigned short us = f2bf(e);
            ls += bf2f(us); af[4 + j] = (short)us;
        }

        // B fragments from LDS (shared by all 4 row-group waves) + MFMA
        const unsigned short* bbase = &ldsw[cur * 8192 + (jwin << 12) + (lane << 3)];
        #pragma unroll
        for (int nt = 0; nt < 8; ++nt) {
            bf16x8 bfr = *(const bf16x8*)(bbase + (nt << 9));
            acc[nt] = __builtin_amdgcn_mfma_f32_16x16x32_bf16(af, bfr, acc[nt], 0, 0, 0);
        }

        // late stage-write into the other buffer
        if (s < 31) {
            *(f32x4*)&ldsw[nxt * 8192 + (t << 4)]     = g0;
            *(f32x4*)&ldsw[nxt * 8192 + (t << 4) + 8] = g1;
        }
        pa0 = na0; pa1 = na1;
        __syncthreads();
    }

    // denominator: reduce per-lane partials across quads; 2 waves per row-group
    ls += __shfl_xor(ls, 16); ls += __shfl_xor(ls, 32);
    if (quad == 0) atomicAdd(&l_red[rg * 16 + n16], ls);

    // cross-wave acc reduction: jwin 0 writes, jwin 1 adds (accbuf aliases stage)
    float* slotp = smem_f + (size_t)(rg * 16) * AS;
    if (jwin == 0) {
        #pragma unroll
        for (int nt = 0; nt < 8; ++nt)
            #pragma unroll
            for (int rr = 0; rr < 4; ++rr)
                slotp[(quad * 4 + rr) * AS + nt * 16 + n16] = acc[nt][rr];
    }
    __syncthreads();
    if (jwin == 1) {
        #pragma unroll
        for (int nt = 0; nt < 8; ++nt)
            #pragma unroll
            for (int rr = 0; rr < 4; ++rr)
                slotp[(quad * 4 + rr) * AS + nt * 16 + n16] += acc[nt][rr];
    }
    __syncthreads();

    // normalize + ELU + coalesced store (64 rows x 128 f)
    float* ob = out + ((size_t)(b * Nn + i0)) * FO;
    #pragma unroll
    for (int c = 0; c < 4; ++c) {
        int flat = c * 2048 + t * 4;
        int m = flat >> 7, f = flat & 127;
        f32x4 v = *(const f32x4*)&smem_f[(size_t)m * AS + f];
        float l = l_red[m];
        f32x4 o;
        #pragma unroll
        for (int j = 0; j < 4; ++j) {
            float x = v[j] / l;
            o[j] = x > 0.f ? x : expm1f(x);
        }
        *(f32x4*)&ob[(size_t)m * FO + f] = o;
    }
}

extern "C" void kernel_launch(void* const* d_in, const int* in_sizes, int n_in,
                              void* d_out, int out_size, void* d_ws, size_t ws_size,
                              hipStream_t stream)
{
    const float* h   = (const float*)d_in[0];
    const int*   adj = (const int*)d_in[1];
    const float* W   = (const float*)d_in[2];
    const float* a   = (const float*)d_in[3];
    float* out = (float*)d_out;

    char* ws = (char*)d_ws;
    unsigned short* Wp  = (unsigned short*)ws;                    // 4 MiB packed
    float* s_src        = (float*)(ws + 4194304);                 // 8 KiB
    float* s_dst        = (float*)(ws + 4259840);                 // 8 KiB
    float* wa           = (float*)(ws + 4325376);                 // 2 KiB
    unsigned int* md_key= (unsigned int*)(ws + 4327424);          // 32 B

    hipLaunchKernelGGL(gat_prep, dim3(8),   dim3(256), 0, stream, W, a, wa, md_key);
    hipLaunchKernelGGL(gat_wh,   dim3(256), dim3(256), 0, stream, h, W, wa, Wp, s_src, s_dst, md_key);
    hipLaunchKernelGGL(gat_attn, dim3(256), dim3(512), 0, stream, adj, Wp, s_src, s_dst, md_key, out);
}

// Round 4
// 247.458 us; speedup vs baseline: 1.0405x; 1.0358x over previous
//
#include <hip/hip_runtime.h>
#include <hip/hip_bf16.h>

#define GAT_ALPHA 0.2f
#define LOG2E 1.4426950408889634f

typedef float f32x4 __attribute__((ext_vector_type(4)));
typedef int   i32x4 __attribute__((ext_vector_type(4)));
typedef short bf16x8 __attribute__((ext_vector_type(8)));

static constexpr int Nn  = 2048;
static constexpr int FIN = 256;
static constexpr int FO  = 128;

static __device__ __forceinline__ unsigned short f2bf(float x) {
    __hip_bfloat16 h = __float2bfloat16(x);
    return __builtin_bit_cast(unsigned short, h);
}
static __device__ __forceinline__ float bf2f(unsigned short u) {
    unsigned int v = ((unsigned int)u) << 16;
    return __builtin_bit_cast(float, v);
}

// ---------------------------------------------------------------------------
// Kernel 0 (prep): wa = W@a (both halves). Inits md_key[8] = 0 (key of -inf).
// ---------------------------------------------------------------------------
__global__ __launch_bounds__(256) void gat_prep(
        const float* __restrict__ W, const float* __restrict__ a,
        float* __restrict__ wa, unsigned int* __restrict__ md_key)
{
    __shared__ float pr[32][8];
    __shared__ float pd[32][8];
    const int t = threadIdx.x;
    const int kl = t >> 3, seg = t & 7;
    const int k = blockIdx.x * 32 + kl;
    float ps = 0.f, pv = 0.f;
    const float* wr = W + (size_t)k * FO + seg * 16;
    #pragma unroll
    for (int f = 0; f < 16; f += 4) {
        f32x4 wv = *(const f32x4*)(wr + f);
        f32x4 as = *(const f32x4*)(a + seg * 16 + f);
        f32x4 ad = *(const f32x4*)(a + FO + seg * 16 + f);
        ps += wv[0]*as[0] + wv[1]*as[1] + wv[2]*as[2] + wv[3]*as[3];
        pv += wv[0]*ad[0] + wv[1]*ad[1] + wv[2]*ad[2] + wv[3]*ad[3];
    }
    pr[kl][seg] = ps; pd[kl][seg] = pv;
    __syncthreads();
    if (t < 32) {
        float s = 0.f, d = 0.f;
        #pragma unroll
        for (int j = 0; j < 8; ++j) { s += pr[t][j]; d += pd[t][j]; }
        wa[blockIdx.x * 32 + t]       = s;
        wa[256 + blockIdx.x * 32 + t] = d;
    }
    if (blockIdx.x == 0 && t < 8) md_key[t] = 0u;   // key(-inf)
}

// ---------------------------------------------------------------------------
// Kernel pack: adj (int32 {0,1}, 134 MB) -> bitmask (4.2 MB).
// Pure dense stream: each wave reads 64 consecutive ints per instruction
// (256 B fully coalesced), 32 independent loads in flight per wave,
// __ballot packs 64 bits -> 2 words. Word w of mask = bits of ints
// [w*32, w*32+32), bit k = (adj[w*32+k] > 0).
// ---------------------------------------------------------------------------
__global__ __launch_bounds__(256) void gat_pack(
        const int* __restrict__ adj, unsigned int* __restrict__ mask)
{
    const int t = threadIdx.x, lane = t & 63, w = t >> 6;
    const size_t ibase = ((size_t)blockIdx.x * 4 + w) * 2048;   // first int of this wave
    const int* src = adj + ibase + lane;
    unsigned int myword = 0;
    #pragma unroll
    for (int c = 0; c < 32; ++c) {
        int v = src[(size_t)c * 64];
        unsigned long long m = __ballot(v > 0);
        if (lane == 2 * c)     myword = (unsigned int)m;
        if (lane == 2 * c + 1) myword = (unsigned int)(m >> 32);
    }
    mask[ibase / 32 + lane] = myword;
}

// ---------------------------------------------------------------------------
// Kernel 1: Wp = bf16(h@W) in PACKED MFMA-B-fragment layout:
//   elem index ((b*64 + v)*8 + nt)*512 + lane*8 + e, where for feature f and
//   node n: v=n>>5, nt=f>>4, lane=((n>>3)&3)*16 + (f&15), e=n&7.
// s_src/s_dst fp32-exact via wa; per-batch max(s_dst) via uint atomicMax.
// ---------------------------------------------------------------------------
__global__ __launch_bounds__(256) void gat_wh(
        const float* __restrict__ h, const float* __restrict__ W,
        const float* __restrict__ wa, unsigned short* __restrict__ Wp,
        float* __restrict__ s_src, float* __restrict__ s_dst,
        unsigned int* __restrict__ md_key)
{
    __shared__ unsigned short WT[FO][264];  // [f][k] bf16, padded
    __shared__ float wal[512];
    __shared__ float sred[64][4][2];
    __shared__ float red64[64];
    const int t  = threadIdx.x;
    const int b  = blockIdx.x & 7;
    const int n0 = (blockIdx.x >> 3) << 6;

    if (t < 128) *(f32x4*)&wal[t * 4] = *(const f32x4*)&wa[t * 4];
    #pragma unroll
    for (int c = 0; c < 32; ++c) {
        int flat = c * 1024 + t * 4;
        int k = flat >> 7, f = flat & 127;
        f32x4 wv = *(const f32x4*)&W[flat];
        WT[f + 0][k] = f2bf(wv[0]);
        WT[f + 1][k] = f2bf(wv[1]);
        WT[f + 2][k] = f2bf(wv[2]);
        WT[f + 3][k] = f2bf(wv[3]);
    }
    __syncthreads();

    {
        const int row = t >> 2, seg = t & 3;
        const float* hp  = h + ((size_t)(b * Nn + n0 + row)) * FIN + seg * 64;
        const float* was = &wal[seg * 64];
        const float* wad = &wal[256 + seg * 64];
        float ps = 0.f, pv = 0.f;
        #pragma unroll
        for (int j = 0; j < 64; j += 4) {
            f32x4 hv = *(const f32x4*)(hp + j);
            f32x4 sv = *(const f32x4*)(was + j);
            f32x4 dv = *(const f32x4*)(wad + j);
            ps += hv[0]*sv[0] + hv[1]*sv[1] + hv[2]*sv[2] + hv[3]*sv[3];
            pv += hv[0]*dv[0] + hv[1]*dv[1] + hv[2]*dv[2] + hv[3]*dv[3];
        }
        sred[row][seg][0] = ps;
        sred[row][seg][1] = pv;
    }
    __syncthreads();
    if (t < 64) {
        float s = sred[t][0][0] + sred[t][1][0] + sred[t][2][0] + sred[t][3][0];
        float d = sred[t][0][1] + sred[t][1][1] + sred[t][2][1] + sred[t][3][1];
        s_src[b * Nn + n0 + t] = s;
        s_dst[b * Nn + n0 + t] = d;
        red64[t] = d;
    }
    __syncthreads();
    if (t < 16) red64[t] = fmaxf(fmaxf(red64[t], red64[t + 16]),
                                 fmaxf(red64[t + 32], red64[t + 48]));
    __syncthreads();
    if (t == 0) {
        float m = red64[0];
        #pragma unroll
        for (int j = 1; j < 16; ++j) m = fmaxf(m, red64[j]);
        unsigned int bits = __builtin_bit_cast(unsigned int, m);
        unsigned int key  = (bits & 0x80000000u) ? ~bits : (bits | 0x80000000u);
        atomicMax(md_key + b, key);
    }

    const int w = t >> 6, lane = t & 63, n16 = lane & 15, quad = lane >> 4;
    const float* ha = h + ((size_t)(b * Nn + n0 + w * 16 + n16)) * FIN + quad * 8;
    f32x4 acc[8] = {};
    #pragma unroll
    for (int ks = 0; ks < 8; ++ks) {
        f32x4 h0 = *(const f32x4*)(ha + ks * 32);
        f32x4 h1 = *(const f32x4*)(ha + ks * 32 + 4);
        bf16x8 af;
        af[0] = (short)f2bf(h0[0]); af[1] = (short)f2bf(h0[1]);
        af[2] = (short)f2bf(h0[2]); af[3] = (short)f2bf(h0[3]);
        af[4] = (short)f2bf(h1[0]); af[5] = (short)f2bf(h1[1]);
        af[6] = (short)f2bf(h1[2]); af[7] = (short)f2bf(h1[3]);
        #pragma unroll
        for (int nt = 0; nt < 8; ++nt) {
            bf16x8 bfr = *(const bf16x8*)&WT[nt * 16 + n16][ks * 32 + quad * 8];
            acc[nt] = __builtin_amdgcn_mfma_f32_16x16x32_bf16(af, bfr, acc[nt], 0, 0, 0);
        }
    }
    // packed write: element (f = nt*16+n16, n = n0 + w*16 + quad*4 + rr)
    {
        const int v      = (n0 >> 5) + (w >> 1);
        const int quad_p = ((w & 1) << 1) + (quad >> 1);
        const int eoff   = (quad & 1) << 2;
        #pragma unroll
        for (int nt = 0; nt < 8; ++nt) {
            ushort4 pk;
            pk.x = f2bf(acc[nt][0]); pk.y = f2bf(acc[nt][1]);
            pk.z = f2bf(acc[nt][2]); pk.w = f2bf(acc[nt][3]);
            size_t idx = ((((size_t)(b << 6) + v) * 8 + nt) * 64 + quad_p * 16 + n16) * 8 + eoff;
            *(ushort4*)&Wp[idx] = pk;
        }
    }
}

// ---------------------------------------------------------------------------
// Kernel 2 (v7): main loop touches global memory ONLY for the L2-resident
// Wp stage. adj replaced by bitmask (16 KB/block, staged to LDS once);
// s_dst staged to LDS once (8 KB). Grid 256 = 32 i-tiles(64 rows) x 8
// batches, 512 threads = 4 row-groups x 2 j-windows, j-tile = 64, Wp
// double-buffered through LDS (all 4 row-group waves share B-fragments).
// ---------------------------------------------------------------------------
__global__ __launch_bounds__(512, 2) void gat_attn(
        const unsigned int* __restrict__ mask, const unsigned short* __restrict__ Wp,
        const float* __restrict__ s_src, const float* __restrict__ s_dst,
        const unsigned int* __restrict__ md_key, float* __restrict__ out)
{
    constexpr int AS = 132;                      // accbuf row stride (f32)
    constexpr int MS = 68;                       // mask row stride (words; 68%16==4 banks spread, 16B-aligned rows)
    __shared__ __align__(16) float smem_f[64 * AS];        // 33792 B: stage bufs / accbuf
    __shared__ __align__(16) unsigned int mlds[64 * MS];   // 17408 B
    __shared__ __align__(16) float dlds[Nn];               // 8192 B
    __shared__ float l_red[64];
    unsigned short* ldsw = (unsigned short*)smem_f;        // 2 x 8192 shorts

    const int t = threadIdx.x, w = t >> 6, lane = t & 63;
    const int n16 = lane & 15, quad = lane >> 4;
    const int rg = w & 3, jwin = w >> 2;
    const int b  = blockIdx.x & 7;
    const int i0 = (blockIdx.x >> 3) << 6;

    if (t < 64) l_red[t] = 0.f;

    // stage mask rows (16 KB contiguous) into padded LDS
    {
        const unsigned int* msrc = mask + ((size_t)(b * Nn + i0)) * 64 + t * 8;
        i32x4 m0 = *(const i32x4*)(msrc);
        i32x4 m1 = *(const i32x4*)(msrc + 4);
        const int r = t >> 3, wd = (t & 7) * 8;
        *(i32x4*)&mlds[r * MS + wd]     = m0;
        *(i32x4*)&mlds[r * MS + wd + 4] = m1;
    }
    // stage s_dst for this batch (8 KB contiguous)
    {
        f32x4 dv = *(const f32x4*)(s_dst + b * Nn + t * 4);
        *(f32x4*)&dlds[t * 4] = dv;
    }

    const unsigned int key = md_key[b];
    const unsigned int mb  = (key & 0x80000000u) ? (key ^ 0x80000000u) : ~key;
    const float mdb = __builtin_bit_cast(float, mb);

    const int row = i0 + rg * 16 + n16;          // this lane's i-row
    const float ssr = s_src[b * Nn + row];
    const float tm  = ssr + mdb;
    const float mi  = fmaxf(tm, GAT_ALPHA * tm) * LOG2E;   // row upper bound
    const float sL  = ssr * LOG2E;

    const int jw = (jwin << 5) + (quad << 3);    // lane's j offset within tile
    const int mrow = (rg * 16 + n16) * MS;       // lane's mask row base (words)
    // packed Wp: batch base b*262144 shorts; tile s chunk = 8192 shorts
    const unsigned short* wsrc = Wp + ((size_t)b << 18) + (t << 4);

    f32x4 acc[8] = {};
    float ls = 0.f;

    // prologue: stage Wp tile 0 into buf 0
    {
        f32x4 g0 = *(const f32x4*)(wsrc);
        f32x4 g1 = *(const f32x4*)(wsrc + 8);
        *(f32x4*)&ldsw[(t << 4)]     = g0;
        *(f32x4*)&ldsw[(t << 4) + 8] = g1;
    }
    __syncthreads();

    for (int s = 0; s < 32; ++s) {
        const int j0  = s << 6;
        const int cur = s & 1, nxt = cur ^ 1;
        // mask byte for this lane's 8 j's (LDS, 2-way max conflict)
        const unsigned int mword = mlds[mrow + s * 2 + jwin];
        const unsigned int mbyte = (mword >> (quad * 8)) & 0xffu;
        // d-values from LDS
        f32x4 d0 = *(const f32x4*)&dlds[j0 + jw];
        f32x4 d1 = *(const f32x4*)&dlds[j0 + jw + 4];
        // issue stage loads for tile s+1 (consumed at loop bottom)
        f32x4 g0, g1;
        if (s < 31) {
            const unsigned short* src = wsrc + (size_t)(s + 1) * 8192;
            g0 = *(const f32x4*)(src);
            g1 = *(const f32x4*)(src + 8);
        }

        // exp -> A fragment (8 consecutive j per lane)
        bf16x8 af;
        #pragma unroll
        for (int j = 0; j < 4; ++j) {
            float u  = __builtin_fmaf(d0[j], LOG2E, sL);
            float lr = fmaxf(u, GAT_ALPHA * u);
            float e  = __builtin_amdgcn_exp2f(lr - mi);
            e = ((mbyte >> j) & 1u) ? e : 0.f;
            unsigned short us = f2bf(e);
            ls += bf2f(us); af[j] = (short)us;
        }
        #pragma unroll
        for (int j = 0; j < 4; ++j) {
            float u  = __builtin_fmaf(d1[j], LOG2E, sL);
            float lr = fmaxf(u, GAT_ALPHA * u);
            float e  = __builtin_amdgcn_exp2f(lr - mi);
            e = ((mbyte >> (4 + j)) & 1u) ? e : 0.f;
            unsigned short us = f2bf(e);
            ls += bf2f(us); af[4 + j] = (short)us;
        }

        // B fragments from LDS (shared by all 4 row-group waves) + MFMA
        const unsigned short* bbase = &ldsw[cur * 8192 + (jwin << 12) + (lane << 3)];
        #pragma unroll
        for (int nt = 0; nt < 8; ++nt) {
            bf16x8 bfr = *(const bf16x8*)(bbase + (nt << 9));
            acc[nt] = __builtin_amdgcn_mfma_f32_16x16x32_bf16(af, bfr, acc[nt], 0, 0, 0);
        }

        // late stage-write into the other buffer
        if (s < 31) {
            *(f32x4*)&ldsw[nxt * 8192 + (t << 4)]     = g0;
            *(f32x4*)&ldsw[nxt * 8192 + (t << 4) + 8] = g1;
        }
        __syncthreads();
    }

    // denominator: reduce per-lane partials across quads; 2 waves per row-group
    ls += __shfl_xor(ls, 16); ls += __shfl_xor(ls, 32);
    if (quad == 0) atomicAdd(&l_red[rg * 16 + n16], ls);

    // cross-wave acc reduction: jwin 0 writes, jwin 1 adds (accbuf aliases stage)
    float* slotp = smem_f + (size_t)(rg * 16) * AS;
    if (jwin == 0) {
        #pragma unroll
        for (int nt = 0; nt < 8; ++nt)
            #pragma unroll
            for (int rr = 0; rr < 4; ++rr)
                slotp[(quad * 4 + rr) * AS + nt * 16 + n16] = acc[nt][rr];
    }
    __syncthreads();
    if (jwin == 1) {
        #pragma unroll
        for (int nt = 0; nt < 8; ++nt)
            #pragma unroll
            for (int rr = 0; rr < 4; ++rr)
                slotp[(quad * 4 + rr) * AS + nt * 16 + n16] += acc[nt][rr];
    }
    __syncthreads();

    // normalize + ELU + coalesced store (64 rows x 128 f)
    float* ob = out + ((size_t)(b * Nn + i0)) * FO;
    #pragma unroll
    for (int c = 0; c < 4; ++c) {
        int flat = c * 2048 + t * 4;
        int m = flat >> 7, f = flat & 127;
        f32x4 v = *(const f32x4*)&smem_f[(size_t)m * AS + f];
        float l = l_red[m];
        f32x4 o;
        #pragma unroll
        for (int j = 0; j < 4; ++j) {
            float x = v[j] / l;
            o[j] = x > 0.f ? x : expm1f(x);
        }
        *(f32x4*)&ob[(size_t)m * FO + f] = o;
    }
}

extern "C" void kernel_launch(void* const* d_in, const int* in_sizes, int n_in,
                              void* d_out, int out_size, void* d_ws, size_t ws_size,
                              hipStream_t stream)
{
    const float* h   = (const float*)d_in[0];
    const int*   adj = (const int*)d_in[1];
    const float* W   = (const float*)d_in[2];
    const float* a   = (const float*)d_in[3];
    float* out = (float*)d_out;

    char* ws = (char*)d_ws;
    unsigned short* Wp  = (unsigned short*)ws;                    // 4 MiB packed
    float* s_src        = (float*)(ws + 4194304);                 // 8 KiB
    float* s_dst        = (float*)(ws + 4259840);                 // 8 KiB
    float* wa           = (float*)(ws + 4325376);                 // 2 KiB
    unsigned int* md_key= (unsigned int*)(ws + 4327424);          // 32 B
    unsigned int* mask  = (unsigned int*)(ws + 8388608);          // 4.2 MiB bitmask

    hipLaunchKernelGGL(gat_prep, dim3(8),    dim3(256), 0, stream, W, a, wa, md_key);
    hipLaunchKernelGGL(gat_wh,   dim3(256),  dim3(256), 0, stream, h, W, wa, Wp, s_src, s_dst, md_key);
    hipLaunchKernelGGL(gat_pack, dim3(4096), dim3(256), 0, stream, adj, mask);
    hipLaunchKernelGGL(gat_attn, dim3(256),  dim3(512), 0, stream, mask, Wp, s_src, s_dst, md_key, out);
}

// Round 5
// 236.070 us; speedup vs baseline: 1.0907x; 1.0482x over previous
//
#include <hip/hip_runtime.h>
#include <hip/hip_bf16.h>

#define GAT_ALPHA 0.2f
#define LOG2E 1.4426950408889634f

typedef float f32x4 __attribute__((ext_vector_type(4)));
typedef int   i32x4 __attribute__((ext_vector_type(4)));
typedef short bf16x8 __attribute__((ext_vector_type(8)));

static constexpr int Nn  = 2048;
static constexpr int FIN = 256;
static constexpr int FO  = 128;

static __device__ __forceinline__ unsigned short f2bf(float x) {
    __hip_bfloat16 h = __float2bfloat16(x);
    return __builtin_bit_cast(unsigned short, h);
}
static __device__ __forceinline__ float bf2f(unsigned short u) {
    unsigned int v = ((unsigned int)u) << 16;
    return __builtin_bit_cast(float, v);
}

// ---------------------------------------------------------------------------
// Kernel 0 (prep): wa = W@a (both halves). Inits md_key[8] = 0 (key of -inf).
// ---------------------------------------------------------------------------
__global__ __launch_bounds__(256) void gat_prep(
        const float* __restrict__ W, const float* __restrict__ a,
        float* __restrict__ wa, unsigned int* __restrict__ md_key)
{
    __shared__ float pr[32][8];
    __shared__ float pd[32][8];
    const int t = threadIdx.x;
    const int kl = t >> 3, seg = t & 7;
    const int k = blockIdx.x * 32 + kl;
    float ps = 0.f, pv = 0.f;
    const float* wr = W + (size_t)k * FO + seg * 16;
    #pragma unroll
    for (int f = 0; f < 16; f += 4) {
        f32x4 wv = *(const f32x4*)(wr + f);
        f32x4 as = *(const f32x4*)(a + seg * 16 + f);
        f32x4 ad = *(const f32x4*)(a + FO + seg * 16 + f);
        ps += wv[0]*as[0] + wv[1]*as[1] + wv[2]*as[2] + wv[3]*as[3];
        pv += wv[0]*ad[0] + wv[1]*ad[1] + wv[2]*ad[2] + wv[3]*ad[3];
    }
    pr[kl][seg] = ps; pd[kl][seg] = pv;
    __syncthreads();
    if (t < 32) {
        float s = 0.f, d = 0.f;
        #pragma unroll
        for (int j = 0; j < 8; ++j) { s += pr[t][j]; d += pd[t][j]; }
        wa[blockIdx.x * 32 + t]       = s;
        wa[256 + blockIdx.x * 32 + t] = d;
    }
    if (blockIdx.x == 0 && t < 8) md_key[t] = 0u;   // key(-inf)
}

// ---------------------------------------------------------------------------
// Kernel 1: Wp = bf16(h@W) in PACKED MFMA-B-fragment layout:
//   elem index ((b*64 + v)*8 + nt)*512 + lane*8 + e, where for feature f and
//   node n: v=n>>5, nt=f>>4, lane=((n>>3)&3)*16 + (f&15), e=n&7.
// s_src/s_dst fp32-exact via wa; per-batch max(s_dst) via uint atomicMax.
// ---------------------------------------------------------------------------
__global__ __launch_bounds__(256) void gat_wh(
        const float* __restrict__ h, const float* __restrict__ W,
        const float* __restrict__ wa, unsigned short* __restrict__ Wp,
        float* __restrict__ s_src, float* __restrict__ s_dst,
        unsigned int* __restrict__ md_key)
{
    __shared__ unsigned short WT[FO][264];  // [f][k] bf16, padded
    __shared__ float wal[512];
    __shared__ float sred[64][4][2];
    __shared__ float red64[64];
    const int t  = threadIdx.x;
    const int b  = blockIdx.x & 7;
    const int n0 = (blockIdx.x >> 3) << 6;

    if (t < 128) *(f32x4*)&wal[t * 4] = *(const f32x4*)&wa[t * 4];
    #pragma unroll
    for (int c = 0; c < 32; ++c) {
        int flat = c * 1024 + t * 4;
        int k = flat >> 7, f = flat & 127;
        f32x4 wv = *(const f32x4*)&W[flat];
        WT[f + 0][k] = f2bf(wv[0]);
        WT[f + 1][k] = f2bf(wv[1]);
        WT[f + 2][k] = f2bf(wv[2]);
        WT[f + 3][k] = f2bf(wv[3]);
    }
    __syncthreads();

    {
        const int row = t >> 2, seg = t & 3;
        const float* hp  = h + ((size_t)(b * Nn + n0 + row)) * FIN + seg * 64;
        const float* was = &wal[seg * 64];
        const float* wad = &wal[256 + seg * 64];
        float ps = 0.f, pv = 0.f;
        #pragma unroll
        for (int j = 0; j < 64; j += 4) {
            f32x4 hv = *(const f32x4*)(hp + j);
            f32x4 sv = *(const f32x4*)(was + j);
            f32x4 dv = *(const f32x4*)(wad + j);
            ps += hv[0]*sv[0] + hv[1]*sv[1] + hv[2]*sv[2] + hv[3]*sv[3];
            pv += hv[0]*dv[0] + hv[1]*dv[1] + hv[2]*dv[2] + hv[3]*dv[3];
        }
        sred[row][seg][0] = ps;
        sred[row][seg][1] = pv;
    }
    __syncthreads();
    if (t < 64) {
        float s = sred[t][0][0] + sred[t][1][0] + sred[t][2][0] + sred[t][3][0];
        float d = sred[t][0][1] + sred[t][1][1] + sred[t][2][1] + sred[t][3][1];
        s_src[b * Nn + n0 + t] = s;
        s_dst[b * Nn + n0 + t] = d;
        red64[t] = d;
    }
    __syncthreads();
    if (t < 16) red64[t] = fmaxf(fmaxf(red64[t], red64[t + 16]),
                                 fmaxf(red64[t + 32], red64[t + 48]));
    __syncthreads();
    if (t == 0) {
        float m = red64[0];
        #pragma unroll
        for (int j = 1; j < 16; ++j) m = fmaxf(m, red64[j]);
        unsigned int bits = __builtin_bit_cast(unsigned int, m);
        unsigned int key  = (bits & 0x80000000u) ? ~bits : (bits | 0x80000000u);
        atomicMax(md_key + b, key);
    }

    const int w = t >> 6, lane = t & 63, n16 = lane & 15, quad = lane >> 4;
    const float* ha = h + ((size_t)(b * Nn + n0 + w * 16 + n16)) * FIN + quad * 8;
    f32x4 acc[8] = {};
    #pragma unroll
    for (int ks = 0; ks < 8; ++ks) {
        f32x4 h0 = *(const f32x4*)(ha + ks * 32);
        f32x4 h1 = *(const f32x4*)(ha + ks * 32 + 4);
        bf16x8 af;
        af[0] = (short)f2bf(h0[0]); af[1] = (short)f2bf(h0[1]);
        af[2] = (short)f2bf(h0[2]); af[3] = (short)f2bf(h0[3]);
        af[4] = (short)f2bf(h1[0]); af[5] = (short)f2bf(h1[1]);
        af[6] = (short)f2bf(h1[2]); af[7] = (short)f2bf(h1[3]);
        #pragma unroll
        for (int nt = 0; nt < 8; ++nt) {
            bf16x8 bfr = *(const bf16x8*)&WT[nt * 16 + n16][ks * 32 + quad * 8];
            acc[nt] = __builtin_amdgcn_mfma_f32_16x16x32_bf16(af, bfr, acc[nt], 0, 0, 0);
        }
    }
    // packed write: element (f = nt*16+n16, n = n0 + w*16 + quad*4 + rr)
    {
        const int v      = (n0 >> 5) + (w >> 1);
        const int quad_p = ((w & 1) << 1) + (quad >> 1);
        const int eoff   = (quad & 1) << 2;
        #pragma unroll
        for (int nt = 0; nt < 8; ++nt) {
            ushort4 pk;
            pk.x = f2bf(acc[nt][0]); pk.y = f2bf(acc[nt][1]);
            pk.z = f2bf(acc[nt][2]); pk.w = f2bf(acc[nt][3]);
            size_t idx = ((((size_t)(b << 6) + v) * 8 + nt) * 64 + quad_p * 16 + n16) * 8 + eoff;
            *(ushort4*)&Wp[idx] = pk;
        }
    }
}

// ---------------------------------------------------------------------------
// Kernel 2 (v8): adj ballot-pack FUSED into the tile loop (pipelined 3 deep):
//   iter s: issue chunk s+3 row-loads (8 x 256B/wave) -> ballot chunk s+2
//   -> mask words land in mlds 2 barriers before use at iter s+2.
// Wave w packs local rows [w*8, w*8+8). No separate pack kernel, no mask
// round-trip. Wp staged through LDS double-buffer with CONFLICT-FREE
// ds_writes (each thread 16 B at byte offset t*16, two linear passes).
// Grid 256 = 32 i-tiles(64 rows) x 8 batches, 512 thr = 4 rg x 2 jwin.
// ---------------------------------------------------------------------------
__global__ __launch_bounds__(512, 2) void gat_attn(
        const int* __restrict__ adj, const unsigned short* __restrict__ Wp,
        const float* __restrict__ s_src, const float* __restrict__ s_dst,
        const unsigned int* __restrict__ md_key, float* __restrict__ out)
{
    constexpr int AS = 132;                      // accbuf row stride (f32)
    constexpr int MS = 68;                       // mask row stride (words)
    __shared__ __align__(16) float smem_f[64 * AS];        // 33792 B: stage bufs / accbuf
    __shared__ __align__(16) unsigned int mlds[64 * MS];   // 17408 B
    __shared__ __align__(16) float dlds[Nn];               // 8192 B
    __shared__ float l_red[64];
    unsigned short* ldsw = (unsigned short*)smem_f;        // 2 x 8192 shorts

    const int t = threadIdx.x, w = t >> 6, lane = t & 63;
    const int n16 = lane & 15, quad = lane >> 4;
    const int rg = w & 3, jwin = w >> 2;
    const int b  = blockIdx.x & 7;
    const int i0 = (blockIdx.x >> 3) << 6;

    if (t < 64) l_red[t] = 0.f;

    // per-wave adj base: wave w owns local rows [w*8, w*8+8)
    const int* abase = adj + ((size_t)(b * Nn + i0 + w * 8)) * Nn + lane;
    // packed Wp batch base
    const unsigned short* wsrc = Wp + ((size_t)b << 18);

    // ---- prologue ----
    // Wp tile-0 stage loads first (oldest vmcnt -> earliest ds_write)
    f32x4 pg0 = *(const f32x4*)(wsrc + t * 8);
    f32x4 pg1 = *(const f32x4*)(wsrc + 4096 + t * 8);
    // pack chunks 0,1 for this wave's 8 rows: load 16, then ballot 16
    int pv[16];
    #pragma unroll
    for (int k = 0; k < 16; ++k) {
        const int rr = k & 7, c = k >> 3;
        pv[k] = abase[(size_t)rr * Nn + (c << 6)];
    }
    // chunk-2 loads (consumed by ballot at iter 0)
    int avQ[8], avP[8];
    #pragma unroll
    for (int rr = 0; rr < 8; ++rr) avQ[rr] = abase[(size_t)rr * Nn + 128];
    // s_dst stage
    *(f32x4*)&dlds[t * 4] = *(const f32x4*)(s_dst + b * Nn + t * 4);

    const unsigned int key = md_key[b];
    const unsigned int mb  = (key & 0x80000000u) ? (key ^ 0x80000000u) : ~key;
    const float mdb = __builtin_bit_cast(float, mb);
    const int row = i0 + rg * 16 + n16;          // this lane's i-row
    const float ssr = s_src[b * Nn + row];
    const float tm  = ssr + mdb;
    const float mi  = fmaxf(tm, GAT_ALPHA * tm) * LOG2E;   // row upper bound
    const float sL  = ssr * LOG2E;
    const int jw   = (jwin << 5) + (quad << 3);  // lane's j offset within tile
    const int mrow = (rg * 16 + n16) * MS;

    // ballot+write chunks 0,1
    #pragma unroll
    for (int k = 0; k < 16; ++k) {
        const int rr = k & 7, c = k >> 3;
        unsigned long long m = __ballot(pv[k] > 0);
        if (lane == 0) mlds[(w * 8 + rr) * MS + (c << 1)]     = (unsigned int)m;
        if (lane == 1) mlds[(w * 8 + rr) * MS + (c << 1) + 1] = (unsigned int)(m >> 32);
    }
    // Wp tile-0 ds_write (conflict-free: 16 B linear per thread, two passes)
    *(f32x4*)&ldsw[t * 8]        = pg0;
    *(f32x4*)&ldsw[4096 + t * 8] = pg1;

    f32x4 acc[8] = {};
    float ls = 0.f;
    __syncthreads();

    // ---- main loop: 2 tiles per iteration (static av double-buffer) ----
#define GAT_TILE(S, CUR, AV_ISSUE, AV_BALLOT)                                   \
    {                                                                           \
        const int s_ = (S);                                                     \
        const int j0_ = s_ << 6;                                                \
        const unsigned int mword = mlds[mrow + (s_ << 1) + jwin];               \
        const unsigned int mbyte = (mword >> (quad * 8)) & 0xffu;               \
        f32x4 d0 = *(const f32x4*)&dlds[j0_ + jw];                              \
        f32x4 d1 = *(const f32x4*)&dlds[j0_ + jw + 4];                          \
        /* adj loads for chunk s+3 (oldest VMEM this iter) */                   \
        if (s_ < 29) {                                                          \
            const int off_ = (s_ + 3) << 6;                                     \
            _Pragma("unroll")                                                   \
            for (int rr = 0; rr < 8; ++rr)                                      \
                AV_ISSUE[rr] = abase[(size_t)rr * Nn + off_];                   \
        }                                                                       \
        /* Wp stage loads for tile s+1 */                                       \
        f32x4 g0, g1;                                                           \
        if (s_ < 31) {                                                          \
            const unsigned short* src_ = wsrc + (size_t)(s_ + 1) * 8192;        \
            g0 = *(const f32x4*)(src_ + t * 8);                                 \
            g1 = *(const f32x4*)(src_ + 4096 + t * 8);                          \
        }                                                                       \
        /* exp -> A fragment */                                                 \
        bf16x8 af;                                                              \
        _Pragma("unroll")                                                       \
        for (int j = 0; j < 4; ++j) {                                           \
            float u  = __builtin_fmaf(d0[j], LOG2E, sL);                        \
            float lr = fmaxf(u, GAT_ALPHA * u);                                 \
            float e  = __builtin_amdgcn_exp2f(lr - mi);                         \
            e = ((mbyte >> j) & 1u) ? e : 0.f;                                  \
            unsigned short us = f2bf(e);                                        \
            ls += bf2f(us); af[j] = (short)us;                                  \
        }                                                                       \
        _Pragma("unroll")                                                       \
        for (int j = 0; j < 4; ++j) {                                           \
            float u  = __builtin_fmaf(d1[j], LOG2E, sL);                        \
            float lr = fmaxf(u, GAT_ALPHA * u);                                 \
            float e  = __builtin_amdgcn_exp2f(lr - mi);                         \
            e = ((mbyte >> (4 + j)) & 1u) ? e : 0.f;                            \
            unsigned short us = f2bf(e);                                        \
            ls += bf2f(us); af[4 + j] = (short)us;                              \
        }                                                                       \
        /* B fragments from LDS + MFMA */                                       \
        const unsigned short* bbase = &ldsw[(CUR) * 8192 + (jwin << 12) + (lane << 3)]; \
        _Pragma("unroll")                                                       \
        for (int nt = 0; nt < 8; ++nt) {                                        \
            bf16x8 bfr = *(const bf16x8*)(bbase + (nt << 9));                   \
            acc[nt] = __builtin_amdgcn_mfma_f32_16x16x32_bf16(af, bfr, acc[nt], 0, 0, 0); \
        }                                                                       \
        /* ballot chunk s+2 (loads issued last iter) + mask write */            \
        if (s_ < 30) {                                                          \
            const int cw_ = (s_ + 2) << 1;                                      \
            _Pragma("unroll")                                                   \
            for (int rr = 0; rr < 8; ++rr) {                                    \
                unsigned long long m = __ballot(AV_BALLOT[rr] > 0);             \
                if (lane == 0) mlds[(w * 8 + rr) * MS + cw_]     = (unsigned int)m; \
                if (lane == 1) mlds[(w * 8 + rr) * MS + cw_ + 1] = (unsigned int)(m >> 32); \
            }                                                                   \
        }                                                                       \
        /* late Wp stage write into other buffer (conflict-free) */             \
        if (s_ < 31) {                                                          \
            *(f32x4*)&ldsw[((CUR) ^ 1) * 8192 + t * 8]        = g0;             \
            *(f32x4*)&ldsw[((CUR) ^ 1) * 8192 + 4096 + t * 8] = g1;             \
        }                                                                       \
        __syncthreads();                                                        \
    }

    for (int s = 0; s < 32; s += 2) {
        GAT_TILE(s,     0, avP, avQ)
        GAT_TILE(s + 1, 1, avQ, avP)
    }
#undef GAT_TILE

    // denominator: reduce per-lane partials across quads; 2 waves per row-group
    ls += __shfl_xor(ls, 16); ls += __shfl_xor(ls, 32);
    if (quad == 0) atomicAdd(&l_red[rg * 16 + n16], ls);

    // cross-wave acc reduction: jwin 0 writes, jwin 1 adds (accbuf aliases stage)
    float* slotp = smem_f + (size_t)(rg * 16) * AS;
    if (jwin == 0) {
        #pragma unroll
        for (int nt = 0; nt < 8; ++nt)
            #pragma unroll
            for (int rr = 0; rr < 4; ++rr)
                slotp[(quad * 4 + rr) * AS + nt * 16 + n16] = acc[nt][rr];
    }
    __syncthreads();
    if (jwin == 1) {
        #pragma unroll
        for (int nt = 0; nt < 8; ++nt)
            #pragma unroll
            for (int rr = 0; rr < 4; ++rr)
                slotp[(quad * 4 + rr) * AS + nt * 16 + n16] += acc[nt][rr];
    }
    __syncthreads();

    // normalize + ELU + coalesced store (64 rows x 128 f)
    float* ob = out + ((size_t)(b * Nn + i0)) * FO;
    #pragma unroll
    for (int c = 0; c < 4; ++c) {
        int flat = c * 2048 + t * 4;
        int m = flat >> 7, f = flat & 127;
        f32x4 v = *(const f32x4*)&smem_f[(size_t)m * AS + f];
        float l = l_red[m];
        f32x4 o;
        #pragma unroll
        for (int j = 0; j < 4; ++j) {
            float x = v[j] / l;
            o[j] = x > 0.f ? x : expm1f(x);
        }
        *(f32x4*)&ob[(size_t)m * FO + f] = o;
    }
}

extern "C" void kernel_launch(void* const* d_in, const int* in_sizes, int n_in,
                              void* d_out, int out_size, void* d_ws, size_t ws_size,
                              hipStream_t stream)
{
    const float* h   = (const float*)d_in[0];
    const int*   adj = (const int*)d_in[1];
    const float* W   = (const float*)d_in[2];
    const float* a   = (const float*)d_in[3];
    float* out = (float*)d_out;

    char* ws = (char*)d_ws;
    unsigned short* Wp  = (unsigned short*)ws;                    // 4 MiB packed
    float* s_src        = (float*)(ws + 4194304);                 // 8 KiB
    float* s_dst        = (float*)(ws + 4259840);                 // 8 KiB
    float* wa           = (float*)(ws + 4325376);                 // 2 KiB
    unsigned int* md_key= (unsigned int*)(ws + 4327424);          // 32 B

    hipLaunchKernelGGL(gat_prep, dim3(8),   dim3(256), 0, stream, W, a, wa, md_key);
    hipLaunchKernelGGL(gat_wh,   dim3(256), dim3(256), 0, stream, h, W, wa, Wp, s_src, s_dst, md_key);
    hipLaunchKernelGGL(gat_attn, dim3(256), dim3(512), 0, stream, adj, Wp, s_src, s_dst, md_key, out);
}